// Round 1
// baseline (258.474 us; speedup 1.0000x reference)
//
#include <hip/hip_runtime.h>
#include <stdint.h>
#include <math.h>

#define HW_ 16384   // H*W = 128*128
#define C_  256

typedef short bf16x8 __attribute__((ext_vector_type(8)));
typedef float f32x4  __attribute__((ext_vector_type(4)));
typedef unsigned int u32;

__device__ __forceinline__ short f2bf(float f) {
  union { float f; unsigned u; } v; v.f = f;
  unsigned u = v.u;
  u += 0x7fffu + ((u >> 16) & 1u);   // RNE
  return (short)(u >> 16);
}

__device__ __forceinline__ void gload_lds16(const void* g, void* l) {
  __builtin_amdgcn_global_load_lds((const __attribute__((address_space(1))) u32*)g,
                                   (__attribute__((address_space(3))) u32*)l, 16, 0, 0);
}

// ---------------- kernel 0: prep (W -> bf16, BN scale/shift) ----------------
__global__ __launch_bounds__(256) void k0_prep(
    const float* __restrict__ w_fe, const float* __restrict__ gamma,
    const float* __restrict__ beta, const float* __restrict__ mean,
    const float* __restrict__ var, unsigned short* __restrict__ Wb,
    float* __restrict__ scale, float* __restrict__ shift)
{
  int i = blockIdx.x * 256 + threadIdx.x;
  if (i < 131072) Wb[i] = (unsigned short)f2bf(w_fe[i]);
  if (i < 256) {
    float sc = gamma[i] * rsqrtf(var[i] + 1e-5f);
    scale[i] = sc;
    shift[i] = beta[i] - mean[i] * sc;
  }
}

// ------- kernel 1: bf16 MFMA GEMM (W x cat) + BN + ReLU + pool-reduce -------
// Block: 256 thr (4 waves). Tile: BM=256 (all channels), BN=64 (16 cols/wave),
// BK=32. Grid: 8 batches * 256 p-tiles = 2048 blocks.
__global__ __launch_bounds__(256) void k1_gemm_pool(
    const float* __restrict__ x1, const float* __restrict__ x2,
    const unsigned short* __restrict__ Wb,
    const float* __restrict__ scale, const float* __restrict__ shift,
    float* __restrict__ pool_sum)
{
  __shared__ unsigned short Alds[256 * 32];   // [channel][k] bf16, 16 KB
  __shared__ float pool_l[256];

  const int tid  = threadIdx.x;
  const int lane = tid & 63;
  const int wave = tid >> 6;
  const int blk  = blockIdx.x;
  const int b    = blk >> 8;           // 256 p-tiles per batch
  const int p0   = (blk & 255) * 64;

  const float* xb1 = x1 + (size_t)b * C_ * HW_;
  const float* xb2 = x2 + (size_t)b * C_ * HW_;

  pool_l[tid] = 0.0f;

  f32x4 acc[16];
#pragma unroll
  for (int i = 0; i < 16; ++i) acc[i] = (f32x4){0.f, 0.f, 0.f, 0.f};

  const int pcol = p0 + wave * 16 + (lane & 15);  // this lane's position (B col)
  const int ioff = (lane >> 4) * 8;               // k-group for both A and B frags

  for (int ks = 0; ks < 16; ++ks) {
    const int k0 = ks * 32;
    // ---- B-operand: gather 8 k-contiguous elements straight from global ----
    const float* src = (k0 < 256)
        ? (xb1 + (size_t)(k0 + ioff) * HW_ + pcol)
        : (xb2 + (size_t)(k0 - 256 + ioff) * HW_ + pcol);
    float g0 = src[0 * HW_], g1 = src[1 * HW_], g2 = src[2 * HW_], g3 = src[3 * HW_];
    float g4 = src[4 * HW_], g5 = src[5 * HW_], g6 = src[6 * HW_], g7 = src[7 * HW_];

    __syncthreads();   // previous iteration's LDS reads complete
    // ---- A-operand: stage W[0:256, k0:k0+32] bf16 into LDS (async DMA) ----
#pragma unroll
    for (int q = 0; q < 4; ++q) {
      int flat8 = q * 256 + tid;                 // 8-element group id
      int row   = flat8 >> 2;
      int kk    = (flat8 & 3) * 8;
      gload_lds16(Wb + row * 512 + k0 + kk,
                  &Alds[q * 2048 + (tid & ~63) * 8]);  // wave-uniform base + lane*16B
    }

    bf16x8 bfr;
    bfr[0] = f2bf(g0); bfr[1] = f2bf(g1); bfr[2] = f2bf(g2); bfr[3] = f2bf(g3);
    bfr[4] = f2bf(g4); bfr[5] = f2bf(g5); bfr[6] = f2bf(g6); bfr[7] = f2bf(g7);

    __syncthreads();   // drains vmcnt(0): A tile staged

#pragma unroll
    for (int mf = 0; mf < 16; ++mf) {
      const bf16x8 af = *(const bf16x8*)&Alds[(mf * 16 + (lane & 15)) * 32 + ioff];
      acc[mf] = __builtin_amdgcn_mfma_f32_16x16x32_bf16(af, bfr, acc[mf], 0, 0, 0);
    }
  }

  // ---- epilogue: BN + ReLU, sum over this wave's 16 positions, pool ----
  const int g4i = (lane >> 4) * 4;
#pragma unroll
  for (int mf = 0; mf < 16; ++mf) {
#pragma unroll
    for (int r = 0; r < 4; ++r) {
      int c = mf * 16 + g4i + r;                 // channel (C/D row)
      float s = acc[mf][r] * scale[c] + shift[c];
      s = fmaxf(s, 0.0f);
      s += __shfl_xor(s, 1);
      s += __shfl_xor(s, 2);
      s += __shfl_xor(s, 4);
      s += __shfl_xor(s, 8);                     // sum over the 16 cols
      if ((lane & 15) == 0) atomicAdd(&pool_l[c], s);
    }
  }
  __syncthreads();
  atomicAdd(&pool_sum[b * C_ + tid], pool_l[tid]);
}

// -------- kernel 2: tiny MLPs -> per-(b,c) 3x3 kernels + attn coefs --------
__global__ __launch_bounds__(256) void k2_small(
    const float* __restrict__ pool_sum,
    const float* __restrict__ w_cg1, const float* __restrict__ w_cg2,
    const float* __restrict__ w_ag1, const float* __restrict__ w_ag2,
    float* __restrict__ cw, float* __restrict__ coef)
{
  __shared__ float pl[256];
  __shared__ float hl[64];
  __shared__ float al[64];
  const int b = blockIdx.x, t = threadIdx.x;
  pl[t] = pool_sum[b * 256 + t] * (1.0f / 16384.0f);
  __syncthreads();
  if (t < 64) {
    float h = 0.f, a = 0.f;
    for (int i = 0; i < 256; ++i) {
      float p = pl[i];
      h += p * w_cg1[t * 256 + i];
      a += p * w_ag1[t * 256 + i];
    }
    hl[t] = fmaxf(h, 0.f);
    al[t] = fmaxf(a, 0.f);
  }
  __syncthreads();
#pragma unroll
  for (int e = 0; e < 9; ++e) {
    int o = e * 256 + t;                 // o in [0,2304) = c*9 + tap
    float s = 0.f;
    for (int j = 0; j < 64; ++j) s += hl[j] * w_cg2[o * 64 + j];
    cw[b * 2304 + o] = s;
  }
  if (t < 2) {
    float s = 0.f;
    for (int j = 0; j < 64; ++j) s += al[j] * w_ag2[t * 64 + j];
    coef[b * 2 + t] = 0.25f / (1.0f + expf(-s));   // 0.25 = LAMBDA_S * LAMBDA_C
  }
}

// -------- kernel 3: depthwise 3x3 (same kernel on x1 & x2) + combine --------
// Block: one 32-row strip of one (b,c) plane. Grid: 8*256*4 = 8192.
__global__ __launch_bounds__(256) void k3_dynconv(
    const float* __restrict__ x1, const float* __restrict__ x2,
    const float* __restrict__ cw, const float* __restrict__ coef,
    float* __restrict__ out)
{
  __shared__ float t1[34 * 128];
  __shared__ float t2[34 * 128];
  const int tid   = threadIdx.x;
  const int blk   = blockIdx.x;
  const int strip = blk & 3;
  const int c     = (blk >> 2) & 255;
  const int b     = blk >> 10;
  const int h0    = strip * 32;

  const size_t plane = ((size_t)b * C_ + c) * HW_;
  const float* p1 = x1 + plane;
  const float* p2 = x2 + plane;

  float tp[9];
#pragma unroll
  for (int e = 0; e < 9; ++e) tp[e] = cw[(b * C_ + c) * 9 + e];
  const float c1 = coef[b * 2 + 0];
  const float c2 = coef[b * 2 + 1];

  // rows h0-1 .. h0+32 (zero-pad outside), 34 rows x 128 cols, float4 loads
  for (int f = tid; f < 1088; f += 256) {
    int row = f >> 5;
    int c4  = (f & 31) << 2;
    int gh  = h0 - 1 + row;
    float4 v1 = make_float4(0.f, 0.f, 0.f, 0.f), v2 = v1;
    if (gh >= 0 && gh < 128) {
      v1 = *(const float4*)&p1[gh * 128 + c4];
      v2 = *(const float4*)&p2[gh * 128 + c4];
    }
    *(float4*)&t1[row * 128 + c4] = v1;
    *(float4*)&t2[row * 128 + c4] = v2;
  }
  __syncthreads();

  for (int i = 0; i < 16; ++i) {
    int q   = tid + i * 256;
    int r   = q >> 7;
    int col = q & 127;
    int lr  = r + 1;
    const bool lok = col > 0, rok = col < 127;
    float d1 = 0.f, d2 = 0.f;
#pragma unroll
    for (int dy = 0; dy < 3; ++dy) {
      const float* row1 = &t1[(lr - 1 + dy) * 128];
      const float* row2 = &t2[(lr - 1 + dy) * 128];
      float a1v = lok ? row1[col - 1] : 0.f;
      float b1v = row1[col];
      float e1v = rok ? row1[col + 1] : 0.f;
      float a2v = lok ? row2[col - 1] : 0.f;
      float b2v = row2[col];
      float e2v = rok ? row2[col + 1] : 0.f;
      d1 += a1v * tp[dy * 3 + 0] + b1v * tp[dy * 3 + 1] + e1v * tp[dy * 3 + 2];
      d2 += a2v * tp[dy * 3 + 0] + b2v * tp[dy * 3 + 1] + e2v * tp[dy * 3 + 2];
    }
    float v1 = t1[lr * 128 + col];
    float v2 = t2[lr * 128 + col];
    out[plane + (size_t)(h0 + r) * 128 + col] = 0.5f * (v1 + v2) + c1 * d1 + c2 * d2;
  }
}

extern "C" void kernel_launch(void* const* d_in, const int* in_sizes, int n_in,
                              void* d_out, int out_size, void* d_ws, size_t ws_size,
                              hipStream_t stream) {
  const float* x1    = (const float*)d_in[0];
  const float* x2    = (const float*)d_in[1];
  const float* w_fe  = (const float*)d_in[2];
  const float* gamma = (const float*)d_in[3];
  const float* beta  = (const float*)d_in[4];
  const float* mean  = (const float*)d_in[5];
  const float* var   = (const float*)d_in[6];
  const float* w_cg1 = (const float*)d_in[7];
  const float* w_cg2 = (const float*)d_in[8];
  const float* w_ag1 = (const float*)d_in[9];
  const float* w_ag2 = (const float*)d_in[10];
  float* out = (float*)d_out;

  // workspace layout (~340 KB)
  char* ws = (char*)d_ws;
  unsigned short* Wb   = (unsigned short*)(ws);            // 262144 B
  float* scale    = (float*)(ws + 262144);                 // 1 KB
  float* shift    = (float*)(ws + 263168);                 // 1 KB
  float* pool_sum = (float*)(ws + 264192);                 // 8 KB
  float* cw       = (float*)(ws + 272384);                 // 73728 B
  float* coef     = (float*)(ws + 346112);                 // 64 B

  hipMemsetAsync(pool_sum, 0, 2048 * sizeof(float), stream);
  k0_prep<<<512, 256, 0, stream>>>(w_fe, gamma, beta, mean, var, Wb, scale, shift);
  k1_gemm_pool<<<2048, 256, 0, stream>>>(x1, x2, Wb, scale, shift, pool_sum);
  k2_small<<<8, 256, 0, stream>>>(pool_sum, w_cg1, w_cg2, w_ag1, w_ag2, cw, coef);
  k3_dynconv<<<8192, 256, 0, stream>>>(x1, x2, cw, coef, out);
}